// Round 3
// baseline (94.069 us; speedup 1.0000x reference)
//
#include <hip/hip_runtime.h>
#include <math.h>

// NodeGate: out[b,n,f] = U[b,n,f] * sigmoid( sum_d silu(mean_f(U[b,n,:])*W1[d]+b1[d]) * W2[d] + b2 )
// B=32, N=4096, F=512, D=64. Pure streaming; one wave handles 4 rows/iter
// (4 independent reduce chains for ILP, 8 loads in flight), nontemporal.

#define FDIM 512

typedef float v4f __attribute__((ext_vector_type(4)));

__global__ __launch_bounds__(256) void nodegate_kernel(
    const float* __restrict__ U,
    const float* __restrict__ W1,   // [D]
    const float* __restrict__ b1,   // [D]
    const float* __restrict__ W2,   // [D]
    const float* __restrict__ b2,   // [1]
    float* __restrict__ out,
    int nquads)                      // nrows / 4
{
    const int lane = threadIdx.x & 63;
    const int wave = threadIdx.x >> 6;
    const int wavesPerBlock = blockDim.x >> 6;
    const int waveId = blockIdx.x * wavesPerBlock + wave;
    const int nWaves = gridDim.x * wavesPerBlock;

    // Gate params: lane d owns hidden unit d (D == 64 == wave size).
    const float w1  = W1[lane];
    const float bb1 = b1[lane];
    const float w2  = W2[lane];
    const float bb2 = b2[0];

    const v4f* __restrict__ src4 = reinterpret_cast<const v4f*>(U);
    v4f* __restrict__ dst4 = reinterpret_cast<v4f*>(out);

    for (int q = waveId; q < nquads; q += nWaves) {
        const size_t base = (size_t)q * 4 * (FDIM / 4);
        // Rows 4q..4q+3: 8 KB contiguous per wave per iteration, 8 loads in flight.
        v4f a0 = __builtin_nontemporal_load(&src4[base + lane]);
        v4f a1 = __builtin_nontemporal_load(&src4[base + lane + 64]);
        v4f b0 = __builtin_nontemporal_load(&src4[base + lane + 128]);
        v4f b1v = __builtin_nontemporal_load(&src4[base + lane + 192]);
        v4f c0 = __builtin_nontemporal_load(&src4[base + lane + 256]);
        v4f c1 = __builtin_nontemporal_load(&src4[base + lane + 320]);
        v4f d0 = __builtin_nontemporal_load(&src4[base + lane + 384]);
        v4f d1 = __builtin_nontemporal_load(&src4[base + lane + 448]);

        float sa = (a0.x + a0.y) + (a0.z + a0.w) + (a1.x + a1.y) + (a1.z + a1.w);
        float sb = (b0.x + b0.y) + (b0.z + b0.w) + (b1v.x + b1v.y) + (b1v.z + b1v.w);
        float sc = (c0.x + c0.y) + (c0.z + c0.w) + (c1.x + c1.y) + (c1.z + c1.w);
        float sd = (d0.x + d0.y) + (d0.z + d0.w) + (d1.x + d1.y) + (d1.z + d1.w);

        // Four independent wave-64 butterflies, interleaved.
        #pragma unroll
        for (int off = 32; off > 0; off >>= 1) {
            sa += __shfl_xor(sa, off, 64);
            sb += __shfl_xor(sb, off, 64);
            sc += __shfl_xor(sc, off, 64);
            sd += __shfl_xor(sd, off, 64);
        }

        const float ma = sa * (1.0f / (float)FDIM);
        const float mb = sb * (1.0f / (float)FDIM);
        const float mc = sc * (1.0f / (float)FDIM);
        const float md = sd * (1.0f / (float)FDIM);

        const float pa = fmaf(ma, w1, bb1);
        const float pb = fmaf(mb, w1, bb1);
        const float pc = fmaf(mc, w1, bb1);
        const float pd = fmaf(md, w1, bb1);
        const float ha = pa / (1.0f + __expf(-pa));     // SiLU
        const float hb = pb / (1.0f + __expf(-pb));
        const float hc = pc / (1.0f + __expf(-pc));
        const float hd = pd / (1.0f + __expf(-pd));
        float ea = ha * w2;
        float eb = hb * w2;
        float ec = hc * w2;
        float ed = hd * w2;
        #pragma unroll
        for (int off = 32; off > 0; off >>= 1) {
            ea += __shfl_xor(ea, off, 64);
            eb += __shfl_xor(eb, off, 64);
            ec += __shfl_xor(ec, off, 64);
            ed += __shfl_xor(ed, off, 64);
        }

        const float ga = 1.0f / (1.0f + __expf(-(ea + bb2)));
        const float gb = 1.0f / (1.0f + __expf(-(eb + bb2)));
        const float gc = 1.0f / (1.0f + __expf(-(ec + bb2)));
        const float gd = 1.0f / (1.0f + __expf(-(ed + bb2)));

        a0 *= ga; a1 *= ga; b0 *= gb; b1v *= gb;
        c0 *= gc; c1 *= gc; d0 *= gd; d1 *= gd;
        __builtin_nontemporal_store(a0,  &dst4[base + lane]);
        __builtin_nontemporal_store(a1,  &dst4[base + lane + 64]);
        __builtin_nontemporal_store(b0,  &dst4[base + lane + 128]);
        __builtin_nontemporal_store(b1v, &dst4[base + lane + 192]);
        __builtin_nontemporal_store(c0,  &dst4[base + lane + 256]);
        __builtin_nontemporal_store(c1,  &dst4[base + lane + 320]);
        __builtin_nontemporal_store(d0,  &dst4[base + lane + 384]);
        __builtin_nontemporal_store(d1,  &dst4[base + lane + 448]);
    }
}

extern "C" void kernel_launch(void* const* d_in, const int* in_sizes, int n_in,
                              void* d_out, int out_size, void* d_ws, size_t ws_size,
                              hipStream_t stream)
{
    const float* U  = (const float*)d_in[0];
    const float* W1 = (const float*)d_in[1];
    const float* b1 = (const float*)d_in[2];
    const float* W2 = (const float*)d_in[3];
    const float* b2 = (const float*)d_in[4];
    float* out = (float*)d_out;

    const int nrows = in_sizes[0] / FDIM;       // B*N = 131072
    const int nquads = nrows / 4;               // 32768 (divisible by construction)
    const int threads = 256;                    // 4 waves/block
    const int wavesPerBlock = threads / 64;
    int blocks = (nquads + wavesPerBlock - 1) / wavesPerBlock;
    if (blocks > 2048) blocks = 2048;           // grid-stride the rest (4 iters/wave exactly)

    hipLaunchKernelGGL(nodegate_kernel, dim3(blocks), dim3(threads), 0, stream,
                       U, W1, b1, W2, b2, out, nquads);
}

// Round 4
// 93.799 us; speedup vs baseline: 1.0029x; 1.0029x over previous
//
#include <hip/hip_runtime.h>
#include <math.h>

// NodeGate: out[b,n,f] = U[b,n,f] * sigmoid( sum_d silu(mean_f(U[b,n,:])*W1[d]+b1[d]) * W2[d] + b2 )
// B=32, N=4096, F=512, D=64. Pure streaming; one wave handles 2 rows/iter
// (independent reduce chains for ILP), nontemporal loads/stores.
// R3 post-mortem: 4 rows/iter regressed (94.1 vs 92.7 µs) -> BW-bound; this
// 2-row version is the best measured (5.79 TB/s = 92% of m13 copy ceiling).

#define FDIM 512

typedef float v4f __attribute__((ext_vector_type(4)));

__global__ __launch_bounds__(256) void nodegate_kernel(
    const float* __restrict__ U,
    const float* __restrict__ W1,   // [D]
    const float* __restrict__ b1,   // [D]
    const float* __restrict__ W2,   // [D]
    const float* __restrict__ b2,   // [1]
    float* __restrict__ out,
    int npairs)                      // nrows / 2
{
    const int lane = threadIdx.x & 63;
    const int wave = threadIdx.x >> 6;
    const int wavesPerBlock = blockDim.x >> 6;
    const int waveId = blockIdx.x * wavesPerBlock + wave;
    const int nWaves = gridDim.x * wavesPerBlock;

    // Gate params: lane d owns hidden unit d (D == 64 == wave size).
    const float w1  = W1[lane];
    const float bb1 = b1[lane];
    const float w2  = W2[lane];
    const float bb2 = b2[0];

    const v4f* __restrict__ src4 = reinterpret_cast<const v4f*>(U);
    v4f* __restrict__ dst4 = reinterpret_cast<v4f*>(out);

    for (int p = waveId; p < npairs; p += nWaves) {
        const size_t base = (size_t)p * 2 * (FDIM / 4);
        // Row A = 2p, Row B = 2p+1. 4 KB contiguous per wave per iteration.
        v4f a0 = __builtin_nontemporal_load(&src4[base + lane]);
        v4f a1 = __builtin_nontemporal_load(&src4[base + lane + 64]);
        v4f c0 = __builtin_nontemporal_load(&src4[base + lane + 128]);
        v4f c1 = __builtin_nontemporal_load(&src4[base + lane + 192]);

        float sa = (a0.x + a0.y) + (a0.z + a0.w) + (a1.x + a1.y) + (a1.z + a1.w);
        float sb = (c0.x + c0.y) + (c0.z + c0.w) + (c1.x + c1.y) + (c1.z + c1.w);

        // Two independent wave-64 butterflies, interleaved by the compiler.
        #pragma unroll
        for (int off = 32; off > 0; off >>= 1) {
            sa += __shfl_xor(sa, off, 64);
            sb += __shfl_xor(sb, off, 64);
        }

        const float ma = sa * (1.0f / (float)FDIM);
        const float mb = sb * (1.0f / (float)FDIM);

        // Excite MLP, lane d computes hidden unit d's contribution.
        const float pa = fmaf(ma, w1, bb1);
        const float pb = fmaf(mb, w1, bb1);
        const float ha = pa / (1.0f + __expf(-pa));     // SiLU
        const float hb = pb / (1.0f + __expf(-pb));
        float da = ha * w2;
        float db = hb * w2;
        #pragma unroll
        for (int off = 32; off > 0; off >>= 1) {
            da += __shfl_xor(da, off, 64);
            db += __shfl_xor(db, off, 64);
        }

        const float ga = 1.0f / (1.0f + __expf(-(da + bb2)));
        const float gb = 1.0f / (1.0f + __expf(-(db + bb2)));

        a0 *= ga; a1 *= ga; c0 *= gb; c1 *= gb;
        __builtin_nontemporal_store(a0, &dst4[base + lane]);
        __builtin_nontemporal_store(a1, &dst4[base + lane + 64]);
        __builtin_nontemporal_store(c0, &dst4[base + lane + 128]);
        __builtin_nontemporal_store(c1, &dst4[base + lane + 192]);
    }
}

extern "C" void kernel_launch(void* const* d_in, const int* in_sizes, int n_in,
                              void* d_out, int out_size, void* d_ws, size_t ws_size,
                              hipStream_t stream)
{
    const float* U  = (const float*)d_in[0];
    const float* W1 = (const float*)d_in[1];
    const float* b1 = (const float*)d_in[2];
    const float* W2 = (const float*)d_in[3];
    const float* b2 = (const float*)d_in[4];
    float* out = (float*)d_out;

    const int nrows = in_sizes[0] / FDIM;       // B*N = 131072
    const int npairs = nrows / 2;               // 65536 (even by construction)
    const int threads = 256;                    // 4 waves/block
    const int wavesPerBlock = threads / 64;
    int blocks = (npairs + wavesPerBlock - 1) / wavesPerBlock;
    if (blocks > 2048) blocks = 2048;           // grid-stride the rest

    hipLaunchKernelGGL(nodegate_kernel, dim3(blocks), dim3(threads), 0, stream,
                       U, W1, b1, W2, b2, out, npairs);
}